// Round 14
// baseline (659.237 us; speedup 1.0000x reference)
//
#include <hip/hip_runtime.h>

#define NN 4096
#define EPS 1e-5f

typedef unsigned long long u64;
union f2u { float f[2]; u64 u; };
typedef float f32x2 __attribute__((ext_vector_type(2)));
typedef float f32x4v __attribute__((ext_vector_type(4)));

// packed fp32 FMA with op_sel broadcast of src1 (VOP3P, 2 FMA/instr):
//  PK_LO: acc.lo += a.lo*b.lo ; acc.hi += a.hi*b.lo   (b.lo broadcast)
//  PK_HI: acc.lo += a.lo*b.hi ; acc.hi += a.hi*b.hi   (b.hi broadcast)
#define PK_LO(acc, a, b) \
  asm("v_pk_fma_f32 %0, %1, %2, %0 op_sel:[0,0,0] op_sel_hi:[1,0,1]" \
      : "+v"(acc) : "v"(a), "v"(b))
#define PK_HI(acc, a, b) \
  asm("v_pk_fma_f32 %0, %1, %2, %0 op_sel:[0,1,0] op_sel_hi:[1,1,1]" \
      : "+v"(acc) : "v"(a), "v"(b))

// ---------------- workspace layout (float offsets) ----------------
#define Q_OFF   0u              // [B][N][8]      131072
#define K_OFF   131072u         // [B][8][N]      131072
#define V_OFF   262144u         // [B][64][N]    1048576
#define O_OFF   1310720u        // PAM out [B][64][N]
#define Y_OFF   2359296u        // y [B][64][N]
#define OC_OFF  3407872u        // CAM raw out
#define AT_OFF  4456448u        // attn_c [B][64][64] 16384
#define S2_OFF  4472832u        // CAM sums: sum[64], sumsq[64]
#define PS_OFF  4472960u        // PAM sums: sum[64], sumsq[64]
#define CNT_OFF 4473088u        // per-(b,mt) arrival counters [256] int32
#define OP_OFF  4473344u        // attn partials [G=4][B][64mt][64m][64c] (4*1048576)
#define LP_OFF  8667648u        // partial row sums [G=4][B][64mt][64m] (4*16384)
// gpart ALIASES op region (op/lp dead after attn kernel)

// ---------------- projections: q,k,v (x staged via LDS) ----------------
// (verbatim r6-r13 — passed)
__global__ __launch_bounds__(256) void proj_kernel(
    const float* __restrict__ x, const float* __restrict__ Wq, const float* __restrict__ bq,
    const float* __restrict__ Wk, const float* __restrict__ bk,
    const float* __restrict__ Wv, const float* __restrict__ bv,
    float* __restrict__ q, float* __restrict__ k, float* __restrict__ v) {
  __shared__ float sWq[8*64], sWk[8*64], sWv[64*64], sbq[8], sbk[8], sbv[64];
  __shared__ float xt[64*68];
  int t = threadIdx.x;
  int b = blockIdx.x >> 6;
  int sp = blockIdx.x & 63;
  int n0 = sp << 6;
  for (int i = t; i < 512; i += 256) { sWq[i] = Wq[i]; sWk[i] = Wk[i]; }
  for (int i = t; i < 4096; i += 256) sWv[i] = Wv[i];
  if (t < 64) sbv[t] = bv[t];
  if (t < 8) { sbq[t] = bq[t]; sbk[t] = bk[t]; }
  for (int i = t; i < 1024; i += 256) {
    int c = i >> 4, nf = (i & 15) << 2;
    *(float4*)&xt[c*68 + nf] =
        *(const float4*)&x[(size_t)(((b<<6)|c)<<12) + n0 + nf];
  }
  __syncthreads();
  int nl = t & 63;
  int n = n0 | nl;
  int cg_ = t >> 6;
  float xv[64];
  #pragma unroll
  for (int c = 0; c < 64; ++c) xv[c] = xt[c*68 + nl];
  for (int c = cg_*16; c < cg_*16+16; ++c) {
    float acc = sbv[c];
    #pragma unroll
    for (int c2 = 0; c2 < 64; ++c2) acc += sWv[c*64 + c2] * xv[c2];
    v[(((b<<6)|c)<<12) | n] = acc;
  }
  if (cg_ == 0) {
    #pragma unroll
    for (int d = 0; d < 8; ++d) {
      float acc = sbq[d];
      #pragma unroll
      for (int c = 0; c < 64; ++c) acc += sWq[d*64+c] * xv[c];
      q[(((b<<12)|n)<<3) | d] = acc;
    }
  } else if (cg_ == 1) {
    #pragma unroll
    for (int d = 0; d < 8; ++d) {
      float acc = sbk[d];
      #pragma unroll
      for (int c = 0; c < 64; ++c) acc += sWk[d*64+c] * xv[c];
      k[(((b<<3)|d)<<12) | n] = acc;
    }
  }
}

// ---------------- flash attention (PAM): 8x8 tile, wave-ni-split PV ----
// vs r13: PV register tile grows 4x4 -> 8x8 per thread (A2[8c][4 m-pairs]),
// with the 4x redundancy resolved by ni-splitting across the 4 waves
// (wave wv handles ni in [16wv,16wv+16)).  PV LDS instrs per wave-chunk:
// 128 -> 64 ds_read_b128, FMA count unchanged (LDS pipe was ~6x VALU in PV,
// r13 analysis).  ni is wave-uniform -> p-reads broadcast over cg lanes,
// v-reads over mg lanes -> <=2-way conflicts.  One-time 3-round LDS tree
// merge of the 4 waves' accumulators at end; op-store pattern, arrival
// protocol, G-merge all byte-identical to r10/r13.
__global__ __launch_bounds__(256, 4) void attn_kernel(
    const float* __restrict__ q, const float* __restrict__ k,
    const float* __restrict__ v, float* __restrict__ op,
    float* __restrict__ lp, float* __restrict__ o,
    float* __restrict__ psums, int* __restrict__ cnt) {
  __shared__ float kst[64*12];   // [ni][d], pad 12; merge: linv[64]
  __shared__ float vst[64*68];   // [ni][c], pad 68; scratch; G-merge sm
  __shared__ float pst[64*68];   // [ni][m], pad 68; scratch
  __shared__ int who;

  const int bi   = blockIdx.x;
  const int g    = bi & 3;
  const int rest = bi >> 2;
  const int mt   = rest & 63;
  const int b    = rest >> 6;
  const int m0   = mt << 6;
  const int t    = threadIdx.x;

  const int rq = t & 15;        // score mapping: rows 4rq..4rq+3
  const int sg = t >> 4;        // score mapping: ni 4sg..4sg+3
  const int wv = t >> 6;        // PV: ni quarter (wave-uniform)
  const int li = t & 63;
  const int mg = li & 7;        // PV: m-octet
  const int cgp = li >> 3;      // PV: c-octet

  // q rows interleaved as pairs (r13-proven)
  f32x2 qq[2][8];
  {
    f32x4v rowv[4][2];
    #pragma unroll
    for (int r = 0; r < 4; ++r) {
      const f32x4v* qp = (const f32x4v*)&q[(size_t)(((b<<12) | (m0 + (rq<<2) + r)) << 3)];
      rowv[r][0] = qp[0]; rowv[r][1] = qp[1];
    }
    #pragma unroll
    for (int p = 0; p < 2; ++p)
      #pragma unroll
      for (int j = 0; j < 8; ++j) {
        f32x2 w;
        w[0] = rowv[2*p][j>>2][j&3];
        w[1] = rowv[2*p+1][j>>2][j&3];
        qq[p][j] = w;
      }
  }

  float lsum[4] = {0.f, 0.f, 0.f, 0.f};
  f32x2 A2[8][4];                // [c-idx][m-pair]: av[mg*8+mp*2+e][cgp*8+c] = A2[c][mp][e]
  #pragma unroll
  for (int c = 0; c < 8; ++c)
    #pragma unroll
    for (int mp = 0; mp < 4; ++mp) A2[c][mp] = (f32x2){0.f, 0.f};

  const int span = NN >> 2;
  const int nbeg = g * span;

  for (int n0 = nbeg; n0 < nbeg + span; n0 += 64) {
    __syncthreads();             // prev PV reads of vst/pst done
    #pragma unroll
    for (int i = t; i < 512; i += 256) {
      int ni = i & 63, d = i >> 6;
      kst[ni*12 + d] = k[(((b<<3)|d)<<12) + n0 + ni];
    }
    #pragma unroll
    for (int i = t; i < 4096; i += 256) {
      int ni = i & 63, c = i >> 6;
      vst[ni*68 + c] = v[(((b<<6)|c)<<12) + n0 + ni];
    }
    __syncthreads();
    // scores (r13 packed, unchanged): thread (rq, sg) -> rows 4rq.., ni 4sg..+3
    #pragma unroll
    for (int j4 = 0; j4 < 4; ++j4) {
      const int ni = (sg << 2) | j4;
      const f32x4v ka = *(const f32x4v*)&kst[ni*12];
      const f32x4v kb = *(const f32x4v*)&kst[ni*12 + 4];
      const f32x2 k01 = __builtin_shufflevector(ka, ka, 0, 1);
      const f32x2 k23 = __builtin_shufflevector(ka, ka, 2, 3);
      const f32x2 k45 = __builtin_shufflevector(kb, kb, 0, 1);
      const f32x2 k67 = __builtin_shufflevector(kb, kb, 2, 3);
      f32x2 s01 = (f32x2){0.f,0.f}, s23 = (f32x2){0.f,0.f};
      PK_LO(s01, qq[0][0], k01); PK_HI(s01, qq[0][1], k01);
      PK_LO(s01, qq[0][2], k23); PK_HI(s01, qq[0][3], k23);
      PK_LO(s01, qq[0][4], k45); PK_HI(s01, qq[0][5], k45);
      PK_LO(s01, qq[0][6], k67); PK_HI(s01, qq[0][7], k67);
      PK_LO(s23, qq[1][0], k01); PK_HI(s23, qq[1][1], k01);
      PK_LO(s23, qq[1][2], k23); PK_HI(s23, qq[1][3], k23);
      PK_LO(s23, qq[1][4], k45); PK_HI(s23, qq[1][5], k45);
      PK_LO(s23, qq[1][6], k67); PK_HI(s23, qq[1][7], k67);
      const float e0 = __expf(s01[0]), e1 = __expf(s01[1]);
      const float e2 = __expf(s23[0]), e3 = __expf(s23[1]);
      lsum[0] += e0; lsum[1] += e1; lsum[2] += e2; lsum[3] += e3;
      *(float4*)&pst[ni*68 + (rq<<2)] = make_float4(e0, e1, e2, e3);
    }
    __syncthreads();
    // PV: wave wv handles 16 ni; thread (mg, cgp): 8m x 8c tile.
    // 4 b128 reads per ni per thread (64 FMA) — half r13's LDS rate.
    #pragma unroll 4
    for (int i = 0; i < 16; ++i) {
      const int ni = (wv << 4) + i;
      const f32x4v pa = *(const f32x4v*)&pst[ni*68 + (mg<<3)];
      const f32x4v pb = *(const f32x4v*)&pst[ni*68 + (mg<<3) + 4];
      const f32x4v va = *(const f32x4v*)&vst[ni*68 + (cgp<<3)];
      const f32x4v vb = *(const f32x4v*)&vst[ni*68 + (cgp<<3) + 4];
      const f32x2 p01 = __builtin_shufflevector(pa, pa, 0, 1);
      const f32x2 p23 = __builtin_shufflevector(pa, pa, 2, 3);
      const f32x2 p45 = __builtin_shufflevector(pb, pb, 0, 1);
      const f32x2 p67 = __builtin_shufflevector(pb, pb, 2, 3);
      const f32x2 v01 = __builtin_shufflevector(va, va, 0, 1);
      const f32x2 v23 = __builtin_shufflevector(va, va, 2, 3);
      const f32x2 v45 = __builtin_shufflevector(vb, vb, 0, 1);
      const f32x2 v67 = __builtin_shufflevector(vb, vb, 2, 3);
      PK_LO(A2[0][0], p01, v01); PK_LO(A2[0][1], p23, v01);
      PK_LO(A2[0][2], p45, v01); PK_LO(A2[0][3], p67, v01);
      PK_HI(A2[1][0], p01, v01); PK_HI(A2[1][1], p23, v01);
      PK_HI(A2[1][2], p45, v01); PK_HI(A2[1][3], p67, v01);
      PK_LO(A2[2][0], p01, v23); PK_LO(A2[2][1], p23, v23);
      PK_LO(A2[2][2], p45, v23); PK_LO(A2[2][3], p67, v23);
      PK_HI(A2[3][0], p01, v23); PK_HI(A2[3][1], p23, v23);
      PK_HI(A2[3][2], p45, v23); PK_HI(A2[3][3], p67, v23);
      PK_LO(A2[4][0], p01, v45); PK_LO(A2[4][1], p23, v45);
      PK_LO(A2[4][2], p45, v45); PK_LO(A2[4][3], p67, v45);
      PK_HI(A2[5][0], p01, v45); PK_HI(A2[5][1], p23, v45);
      PK_HI(A2[5][2], p45, v45); PK_HI(A2[5][3], p67, v45);
      PK_LO(A2[6][0], p01, v67); PK_LO(A2[6][1], p23, v67);
      PK_LO(A2[6][2], p45, v67); PK_LO(A2[6][3], p67, v67);
      PK_HI(A2[7][0], p01, v67); PK_HI(A2[7][1], p23, v67);
      PK_HI(A2[7][2], p45, v67); PK_HI(A2[7][3], p67, v67);
    }
  }
  // ---- 3-round LDS tree merge of the 4 waves' accumulators ----
  __syncthreads();               // all PV reads of vst/pst done
  {
    // publish/accumulate helpers via flat [li*68 + j] (16B-aligned, j=0..63)
    #define PUBLISH(buf)                                                        \
      { _Pragma("unroll")                                                       \
        for (int c = 0; c < 8; ++c) {                                           \
          f32x4v lo = __builtin_shufflevector(A2[c][0], A2[c][1], 0,1,2,3);     \
          f32x4v hi = __builtin_shufflevector(A2[c][2], A2[c][3], 0,1,2,3);     \
          *(f32x4v*)&(buf)[li*68 + (c<<3)]     = lo;                            \
          *(f32x4v*)&(buf)[li*68 + (c<<3) + 4] = hi;                            \
        } }
    #define ACCUM(buf)                                                          \
      { _Pragma("unroll")                                                       \
        for (int c = 0; c < 8; ++c) {                                           \
          f32x4v lo = *(const f32x4v*)&(buf)[li*68 + (c<<3)];                   \
          f32x4v hi = *(const f32x4v*)&(buf)[li*68 + (c<<3) + 4];               \
          A2[c][0][0] += lo[0]; A2[c][0][1] += lo[1];                           \
          A2[c][1][0] += lo[2]; A2[c][1][1] += lo[3];                           \
          A2[c][2][0] += hi[0]; A2[c][2][1] += hi[1];                           \
          A2[c][3][0] += hi[2]; A2[c][3][1] += hi[3];                           \
        } }
    if (wv == 2) PUBLISH(pst);
    if (wv == 3) PUBLISH(vst);
    __syncthreads();
    if (wv == 0) ACCUM(pst);
    if (wv == 1) ACCUM(vst);
    __syncthreads();
    if (wv == 1) PUBLISH(pst);
    __syncthreads();
    if (wv == 0) ACCUM(pst);
    __syncthreads();
    #undef PUBLISH
    #undef ACCUM
  }
  // lsum partials into pst scratch (old mapping) + wave0 writes tile to vst
  *(float4*)&pst[sg*68 + (rq<<2)] = make_float4(lsum[0], lsum[1], lsum[2], lsum[3]);
  if (wv == 0) {
    #pragma unroll
    for (int mp = 0; mp < 4; ++mp)
      #pragma unroll
      for (int e = 0; e < 2; ++e) {
        const int row = (mg<<3) + (mp<<1) + e;
        f32x4v w0, w1;
        w0[0] = A2[0][mp][e]; w0[1] = A2[1][mp][e];
        w0[2] = A2[2][mp][e]; w0[3] = A2[3][mp][e];
        w1[0] = A2[4][mp][e]; w1[1] = A2[5][mp][e];
        w1[2] = A2[6][mp][e]; w1[3] = A2[7][mp][e];
        *(f32x4v*)&vst[row*68 + (cgp<<3)]     = w0;
        *(f32x4v*)&vst[row*68 + (cgp<<3) + 4] = w1;
      }
  }
  __syncthreads();
  if (t < 64) {
    float l = 0.f;
    #pragma unroll
    for (int s = 0; s < 16; ++s) l += pst[s*68 + t];
    __hip_atomic_store(&lp[(((((g<<2)|b)<<6) | mt)<<6) | t], l,
                       __ATOMIC_RELAXED, __HIP_MEMORY_SCOPE_AGENT);
  }
  // all threads: op partial stores, r13-identical layout (read tile from vst)
  float* ob = op + ((size_t)((((g<<2)|b)<<6) | mt) << 12);
  #pragma unroll
  for (int r = 0; r < 4; ++r) {
    const int m = (sg<<2) | r;
    const float4 vv = *(const float4*)&vst[m*68 + (rq<<2)];
    const int base = (m<<6) | (rq<<2);
    f2u lo, hi;
    lo.f[0] = vv.x; lo.f[1] = vv.y;
    hi.f[0] = vv.z; hi.f[1] = vv.w;
    __hip_atomic_store((u64*)&ob[base],     lo.u, __ATOMIC_RELAXED, __HIP_MEMORY_SCOPE_AGENT);
    __hip_atomic_store((u64*)&ob[base + 2], hi.u, __ATOMIC_RELAXED, __HIP_MEMORY_SCOPE_AGENT);
  }

  // ---- arrival protocol (r10-proven) ----
  __syncthreads();
  if (t == 0)
    who = __hip_atomic_fetch_add(&cnt[(b<<6) | mt], 1,
                                 __ATOMIC_RELEASE, __HIP_MEMORY_SCOPE_AGENT);
  __syncthreads();
  if (who != 3) return;
  if (t == 0)
    __builtin_amdgcn_fence(__ATOMIC_ACQUIRE, "agent");  // buffer_inv: drop stale L2
  __syncthreads();

  // ---- inline G-merge (r10-proven; plain loads post-invalidate) ----
  float* sm = vst;
  float* linv = kst;
  if (t < 64) {
    float l = 0.f;
    #pragma unroll
    for (int g2 = 0; g2 < 4; ++g2)
      l += lp[(((((g2<<2)|b)<<6) | mt)<<6) | t];
    linv[t] = 1.f / l;
  }
  __syncthreads();
  for (int i = 0; i < 16; ++i) {
    int idx = (i<<8) + t;
    float s = 0.f;
    #pragma unroll
    for (int g2 = 0; g2 < 4; ++g2)
      s += op[((size_t)((((g2<<2)|b)<<6) | mt) << 12) + idx];
    int m = idx >> 6, c = idx & 63;
    sm[c*65 + m] = s * linv[m];
  }
  __syncthreads();
  for (int i = 0; i < 16; ++i) {
    int idx = (i<<8) + t;
    int m = idx & 63, c = idx >> 6;
    float ov = sm[c*65 + m];
    o[(((b<<6)|c)<<12) | (mt<<6) | m] = ov;
    float s1 = ov, s2 = ov*ov;
    #pragma unroll
    for (int off2 = 32; off2; off2 >>= 1) {
      s1 += __shfl_xor(s1, off2, 64);
      s2 += __shfl_xor(s2, off2, 64);
    }
    if ((t & 63) == 0) { atomicAdd(&psums[c], s1); atomicAdd(&psums[64+c], s2); }
  }
}

// ---------------- yg: BN1 coefs + y = o*A1+B1+x + gram partials ----------------
// (verbatim round 12/13 — passed)
__global__ __launch_bounds__(256) void yg_kernel(
    const float* __restrict__ o, const float* __restrict__ x,
    const float* __restrict__ psums,
    const float* __restrict__ gp, const float* __restrict__ w1, const float* __restrict__ bb1,
    float* __restrict__ y, float* __restrict__ gpart) {
  __shared__ float yt[64*36];    // [c][m32], stride 36
  __shared__ float cf[128];
  const int bi = blockIdx.x;
  const int b = bi >> 7, sp = bi & 127;
  const int t = threadIdx.x;
  const int n0 = sp << 5;
  if (t < 64) {
    float m1 = psums[t] * (1.f/16384.f), m2 = psums[64+t] * (1.f/16384.f);
    float var = m2 - m1*m1;
    float gg = *gp;
    float r = rsqrtf(gg*gg*var + EPS);
    float a = gg * r * w1[t];
    cf[t] = a; cf[64+t] = bb1[t] - m1*a;
  }
  __syncthreads();
  #pragma unroll
  for (int i = 0; i < 8; ++i) {
    int idx = (i<<8) + t;
    int c = idx >> 5, m = idx & 31;
    size_t gi = ((size_t)(((b<<6)|c)<<12)) + n0 + m;
    float yv = o[gi]*cf[c] + cf[64+c] + x[gi];
    yt[c*36 + m] = yv;
    y[gi] = yv;
  }
  __syncthreads();
  {
    int tc = t >> 4, td = t & 15;
    float acc[4][4] = {{0.f}};
    #pragma unroll
    for (int mj = 0; mj < 8; ++mj) {
      float4 ya[4], yb[4];
      #pragma unroll
      for (int r = 0; r < 4; ++r)  ya[r] = *(const float4*)&yt[((tc<<2)+r)*36 + (mj<<2)];
      #pragma unroll
      for (int ss = 0; ss < 4; ++ss) yb[ss] = *(const float4*)&yt[((td<<2)+ss)*36 + (mj<<2)];
      #pragma unroll
      for (int r = 0; r < 4; ++r)
        #pragma unroll
        for (int ss = 0; ss < 4; ++ss)
          acc[r][ss] += ya[r].x*yb[ss].x + ya[r].y*yb[ss].y + ya[r].z*yb[ss].z + ya[r].w*yb[ss].w;
    }
    float* gb = gpart + ((size_t)bi << 12);
    #pragma unroll
    for (int r = 0; r < 4; ++r)
      *(float4*)&gb[(((tc<<2)+r)<<6) | (td<<2)] =
          make_float4(acc[r][0], acc[r][1], acc[r][2], acc[r][3]);
  }
}

// ---------------- csm: reduce 128 gram partials + row softmax -> attnc ----------------
// (verbatim round 12/13 — passed)
__global__ __launch_bounds__(256) void csm_kernel(
    const float* __restrict__ gpart, float* __restrict__ attnc) {
  __shared__ float red[256];
  const int bi = blockIdx.x;
  const int b = bi >> 6, row = bi & 63;
  const int t = threadIdx.x;
  const int d = t & 63, spg = t >> 6;
  float e = 0.f;
  #pragma unroll
  for (int jj = 0; jj < 32; ++jj) {
    int ch = (spg<<5) + jj;
    e += gpart[((size_t)((b<<7)|ch) << 12) + (row<<6) + d];
  }
  red[t] = e;
  __syncthreads();
  if (t < 64) {
    float ee = red[t]+red[64+t]+red[128+t]+red[192+t];
    float mn = ee;
    #pragma unroll
    for (int off = 32; off; off >>= 1) mn = fminf(mn, __shfl_xor(mn, off, 64));
    float p = __expf(mn - ee);           // softmax(max-e) == exp(min-e)/sum
    float s = p;
    #pragma unroll
    for (int off = 32; off; off >>= 1) s += __shfl_xor(s, off, 64);
    attnc[(((b<<6)|row)<<6) | t] = p / s;
  }
}

// ---------------- out_c = attn_c @ y  (+ fused BN2 stats) ----------------
// (verbatim round 12/13 — passed)
__global__ __launch_bounds__(256) void cam_apply_kernel(
    const float* __restrict__ attn, const float* __restrict__ y,
    float* __restrict__ oc, float* __restrict__ sums) {
  __shared__ float satt[64*68];
  const int bi = blockIdx.x;
  const int b = bi >> 7, sp = bi & 127;
  const int n0 = sp << 5;
  const int t = threadIdx.x;
  const int nl = t & 31, cg_ = t >> 5;
  for (int i = t; i < 4096; i += 256)
    satt[(i>>6)*68 + (i&63)] = attn[(b<<12) | i];
  __syncthreads();
  float yv[64];
  #pragma unroll
  for (int d = 0; d < 64; ++d)
    yv[d] = y[((size_t)(((b<<6)|d)<<12)) + n0 + nl];
  #pragma unroll
  for (int j = 0; j < 8; ++j) {
    int c = (cg_<<3) + j;
    float acc = 0.f;
    #pragma unroll
    for (int d4 = 0; d4 < 16; ++d4) {
      float4 avv = *(const float4*)&satt[c*68 + (d4<<2)];
      acc += avv.x*yv[d4*4] + avv.y*yv[d4*4+1] + avv.z*yv[d4*4+2] + avv.w*yv[d4*4+3];
    }
    oc[((size_t)(((b<<6)|c)<<12)) + n0 + nl] = acc;
    float s1 = acc, s2 = acc*acc;
    #pragma unroll
    for (int off = 16; off; off >>= 1) {
      s1 += __shfl_xor(s1, off, 64);
      s2 += __shfl_xor(s2, off, 64);
    }
    if ((t & 31) == 0) { atomicAdd(&sums[c], s1); atomicAdd(&sums[64+c], s2); }
  }
}

// ---------------- fin: BN2 coefs + out = oc*A2 + B2 + y (elementwise) ----------------
// (verbatim round 12/13 — passed)
__global__ __launch_bounds__(256) void fin_kernel(
    const float* __restrict__ oc, const float* __restrict__ y,
    const float* __restrict__ s2b,
    const float* __restrict__ gc, const float* __restrict__ w2, const float* __restrict__ bb2,
    float* __restrict__ out) {
  __shared__ float cf[128];
  const int t = threadIdx.x;
  if (t < 64) {
    float m1 = s2b[t] * (1.f/16384.f), m2 = s2b[64+t] * (1.f/16384.f);
    float var = m2 - m1*m1;
    float gg = *gc;
    float r = rsqrtf(gg*gg*var + EPS);
    float a = gg * r * w2[t];
    cf[t] = a; cf[64+t] = bb2[t] - m1*a;
  }
  __syncthreads();
  const int off = (blockIdx.x*256 + t) << 2;
  const int c = (off >> 12) & 63;
  const float a = cf[c], bb = cf[64+c];
  const float4 o4 = *(const float4*)&oc[off];
  const float4 y4 = *(const float4*)&y[off];
  float4 r4;
  r4.x = o4.x*a + bb + y4.x;
  r4.y = o4.y*a + bb + y4.y;
  r4.z = o4.z*a + bb + y4.z;
  r4.w = o4.w*a + bb + y4.w;
  *(float4*)&out[off] = r4;
}

extern "C" void kernel_launch(void* const* d_in, const int* in_sizes, int n_in,
                              void* d_out, int out_size, void* d_ws, size_t ws_size,
                              hipStream_t stream) {
  (void)in_sizes; (void)n_in; (void)out_size; (void)ws_size;
  const float* x      = (const float*)d_in[0];
  const float* Wq     = (const float*)d_in[1];
  const float* bq     = (const float*)d_in[2];
  const float* Wk     = (const float*)d_in[3];
  const float* bk     = (const float*)d_in[4];
  const float* Wv     = (const float*)d_in[5];
  const float* bv     = (const float*)d_in[6];
  const float* gp     = (const float*)d_in[7];
  const float* bnp_w  = (const float*)d_in[8];
  const float* bnp_b  = (const float*)d_in[9];
  const float* gc     = (const float*)d_in[10];
  const float* bnc_w  = (const float*)d_in[11];
  const float* bnc_b  = (const float*)d_in[12];

  float* ws = (float*)d_ws;
  float* q     = ws + Q_OFF;
  float* k     = ws + K_OFF;
  float* v     = ws + V_OFF;
  float* o     = ws + O_OFF;
  float* y     = ws + Y_OFF;
  float* oc    = ws + OC_OFF;
  float* atc   = ws + AT_OFF;
  float* s2b   = ws + S2_OFF;
  float* ps    = ws + PS_OFF;
  int*   cnt   = (int*)(ws + CNT_OFF);
  float* op    = ws + OP_OFF;
  float* lpart = ws + LP_OFF;
  float* gpart = op;             // aliases op region (dead after attn)

  // zero s2b(128) + ps(128) + cnt(256) — contiguous 512 words
  hipMemsetAsync(s2b, 0, 512u * sizeof(float), stream);

  proj_kernel<<<256, 256, 0, stream>>>(x, Wq, bq, Wk, bk, Wv, bv, q, k, v);
  attn_kernel<<<1024, 256, 0, stream>>>(q, k, v, op, lpart, o, ps, cnt);
  yg_kernel<<<512, 256, 0, stream>>>(o, x, ps, gp, bnp_w, bnp_b, y, gpart);
  csm_kernel<<<256, 256, 0, stream>>>(gpart, atc);
  cam_apply_kernel<<<512, 256, 0, stream>>>(atc, y, oc, s2b);
  fin_kernel<<<1024, 256, 0, stream>>>(oc, y, s2b, gc, bnc_w, bnc_b, (float*)d_out);
}

// Round 15
// 469.149 us; speedup vs baseline: 1.4052x; 1.4052x over previous
//
#include <hip/hip_runtime.h>

#define NN 4096
#define EPS 1e-5f

typedef unsigned long long u64;
union f2u { float f[2]; u64 u; };
typedef float f32x2 __attribute__((ext_vector_type(2)));
typedef float f32x4v __attribute__((ext_vector_type(4)));

// packed fp32 FMA with op_sel broadcast of src1 (VOP3P, 2 FMA/instr):
//  PK_LO: acc.lo += a.lo*b.lo ; acc.hi += a.hi*b.lo   (b.lo broadcast)
//  PK_HI: acc.lo += a.lo*b.hi ; acc.hi += a.hi*b.hi   (b.hi broadcast)
#define PK_LO(acc, a, b) \
  asm("v_pk_fma_f32 %0, %1, %2, %0 op_sel:[0,0,0] op_sel_hi:[1,0,1]" \
      : "+v"(acc) : "v"(a), "v"(b))
#define PK_HI(acc, a, b) \
  asm("v_pk_fma_f32 %0, %1, %2, %0 op_sel:[0,1,0] op_sel_hi:[1,1,1]" \
      : "+v"(acc) : "v"(a), "v"(b))

// ---------------- workspace layout (float offsets) ----------------
#define Q_OFF   0u              // [B][N][8]      131072
#define K_OFF   131072u         // [B][8][N]      131072
#define V_OFF   262144u         // [B][64][N]    1048576
#define O_OFF   1310720u        // PAM out [B][64][N]
#define Y_OFF   2359296u        // y [B][64][N]
#define OC_OFF  3407872u        // CAM raw out
#define AT_OFF  4456448u        // attn_c [B][64][64] 16384
#define S2_OFF  4472832u        // CAM sums: sum[64], sumsq[64]
#define PS_OFF  4472960u        // PAM sums: sum[64], sumsq[64]
#define CNT_OFF 4473088u        // per-(b,mt) arrival counters [256] int32
#define OP_OFF  4473344u        // attn partials [G=4][B][64mt][64m][64c] (4*1048576)
#define LP_OFF  8667648u        // partial row sums [G=4][B][64mt][64m] (4*16384)
// gpart ALIASES op region (op/lp dead after attn kernel)

// ---------------- projections: q,k,v (x staged via LDS) ----------------
// (verbatim r6-r13 — passed)
__global__ __launch_bounds__(256) void proj_kernel(
    const float* __restrict__ x, const float* __restrict__ Wq, const float* __restrict__ bq,
    const float* __restrict__ Wk, const float* __restrict__ bk,
    const float* __restrict__ Wv, const float* __restrict__ bv,
    float* __restrict__ q, float* __restrict__ k, float* __restrict__ v) {
  __shared__ float sWq[8*64], sWk[8*64], sWv[64*64], sbq[8], sbk[8], sbv[64];
  __shared__ float xt[64*68];
  int t = threadIdx.x;
  int b = blockIdx.x >> 6;
  int sp = blockIdx.x & 63;
  int n0 = sp << 6;
  for (int i = t; i < 512; i += 256) { sWq[i] = Wq[i]; sWk[i] = Wk[i]; }
  for (int i = t; i < 4096; i += 256) sWv[i] = Wv[i];
  if (t < 64) sbv[t] = bv[t];
  if (t < 8) { sbq[t] = bq[t]; sbk[t] = bk[t]; }
  for (int i = t; i < 1024; i += 256) {
    int c = i >> 4, nf = (i & 15) << 2;
    *(float4*)&xt[c*68 + nf] =
        *(const float4*)&x[(size_t)(((b<<6)|c)<<12) + n0 + nf];
  }
  __syncthreads();
  int nl = t & 63;
  int n = n0 | nl;
  int cg_ = t >> 6;
  float xv[64];
  #pragma unroll
  for (int c = 0; c < 64; ++c) xv[c] = xt[c*68 + nl];
  for (int c = cg_*16; c < cg_*16+16; ++c) {
    float acc = sbv[c];
    #pragma unroll
    for (int c2 = 0; c2 < 64; ++c2) acc += sWv[c*64 + c2] * xv[c2];
    v[(((b<<6)|c)<<12) | n] = acc;
  }
  if (cg_ == 0) {
    #pragma unroll
    for (int d = 0; d < 8; ++d) {
      float acc = sbq[d];
      #pragma unroll
      for (int c = 0; c < 64; ++c) acc += sWq[d*64+c] * xv[c];
      q[(((b<<12)|n)<<3) | d] = acc;
    }
  } else if (cg_ == 1) {
    #pragma unroll
    for (int d = 0; d < 8; ++d) {
      float acc = sbk[d];
      #pragma unroll
      for (int c = 0; c < 64; ++c) acc += sWk[d*64+c] * xv[c];
      k[(((b<<3)|d)<<12) | n] = acc;
    }
  }
}

// ---------------- flash attention (PAM): 8x4 tile, 2-way wave-ni-split PV ----
// r14 retry with HALF the register pressure (r14's 8x8 spilled: FETCH 806MB
// scratch traffic at VGPR cap; the split/merge LOGIC passed correctness).
// Waves {0,1} handle ni 0..31, waves {2,3} ni 32..63.  Thread tile 8m x 4c
// (A2 = 16 f32x2 = 32 VGPR).  PV LDS: 3 b128 per 32 FMA -> 96 wave-instrs
// per chunk (r13: 128).  One publish/accum merge round (wave2->pst,
// wave3->vst; waves 0/1 accumulate same-li2 partner), then waves 0/1 store
// op directly from registers in the r13-identical layout.  Scores, staging,
// lsum, arrival protocol, G-merge: verbatim r13.
__global__ __launch_bounds__(256, 4) void attn_kernel(
    const float* __restrict__ q, const float* __restrict__ k,
    const float* __restrict__ v, float* __restrict__ op,
    float* __restrict__ lp, float* __restrict__ o,
    float* __restrict__ psums, int* __restrict__ cnt) {
  __shared__ float kst[64*12];   // [ni][d], pad 12; merge: linv[64]
  __shared__ float vst[64*68];   // [ni][c], pad 68; scratch; G-merge sm
  __shared__ float pst[64*68];   // [ni][m], pad 68; scratch
  __shared__ int who;

  const int bi   = blockIdx.x;
  const int g    = bi & 3;
  const int rest = bi >> 2;
  const int mt   = rest & 63;
  const int b    = rest >> 6;
  const int m0   = mt << 6;
  const int t    = threadIdx.x;

  const int rq = t & 15;        // score mapping: rows 4rq..4rq+3
  const int sg = t >> 4;        // score mapping: ni 4sg..4sg+3
  const int wv = t >> 6;        // wave 0..3
  const int li = t & 63;
  const int h   = wv >> 1;      // ni half (0: ni 0..31, 1: ni 32..63)
  const int li2 = ((wv & 1) << 6) | li;   // 0..127 within half
  const int mg = li2 >> 4;      // m-octet (8 rows)
  const int cq = li2 & 15;      // c-quad  (4 cols)

  // q rows interleaved as pairs (r13-proven)
  f32x2 qq[2][8];
  {
    f32x4v rowv[4][2];
    #pragma unroll
    for (int r = 0; r < 4; ++r) {
      const f32x4v* qp = (const f32x4v*)&q[(size_t)(((b<<12) | (m0 + (rq<<2) + r)) << 3)];
      rowv[r][0] = qp[0]; rowv[r][1] = qp[1];
    }
    #pragma unroll
    for (int p = 0; p < 2; ++p)
      #pragma unroll
      for (int j = 0; j < 8; ++j) {
        f32x2 w;
        w[0] = rowv[2*p][j>>2][j&3];
        w[1] = rowv[2*p+1][j>>2][j&3];
        qq[p][j] = w;
      }
  }

  float lsum[4] = {0.f, 0.f, 0.f, 0.f};
  f32x2 A2[4][4];               // [c][m-pair]: av[mg*8+2mp+e][cq*4+c] = A2[c][mp][e]
  #pragma unroll
  for (int c = 0; c < 4; ++c)
    #pragma unroll
    for (int mp = 0; mp < 4; ++mp) A2[c][mp] = (f32x2){0.f, 0.f};

  const int span = NN >> 2;
  const int nbeg = g * span;

  for (int n0 = nbeg; n0 < nbeg + span; n0 += 64) {
    __syncthreads();             // prev PV reads of vst/pst done
    #pragma unroll
    for (int i = t; i < 512; i += 256) {
      int ni = i & 63, d = i >> 6;
      kst[ni*12 + d] = k[(((b<<3)|d)<<12) + n0 + ni];
    }
    #pragma unroll
    for (int i = t; i < 4096; i += 256) {
      int ni = i & 63, c = i >> 6;
      vst[ni*68 + c] = v[(((b<<6)|c)<<12) + n0 + ni];
    }
    __syncthreads();
    // scores (r13 packed, unchanged): thread (rq, sg) -> rows 4rq.., ni 4sg..+3
    #pragma unroll
    for (int j4 = 0; j4 < 4; ++j4) {
      const int ni = (sg << 2) | j4;
      const f32x4v ka = *(const f32x4v*)&kst[ni*12];
      const f32x4v kb = *(const f32x4v*)&kst[ni*12 + 4];
      const f32x2 k01 = __builtin_shufflevector(ka, ka, 0, 1);
      const f32x2 k23 = __builtin_shufflevector(ka, ka, 2, 3);
      const f32x2 k45 = __builtin_shufflevector(kb, kb, 0, 1);
      const f32x2 k67 = __builtin_shufflevector(kb, kb, 2, 3);
      f32x2 s01 = (f32x2){0.f,0.f}, s23 = (f32x2){0.f,0.f};
      PK_LO(s01, qq[0][0], k01); PK_HI(s01, qq[0][1], k01);
      PK_LO(s01, qq[0][2], k23); PK_HI(s01, qq[0][3], k23);
      PK_LO(s01, qq[0][4], k45); PK_HI(s01, qq[0][5], k45);
      PK_LO(s01, qq[0][6], k67); PK_HI(s01, qq[0][7], k67);
      PK_LO(s23, qq[1][0], k01); PK_HI(s23, qq[1][1], k01);
      PK_LO(s23, qq[1][2], k23); PK_HI(s23, qq[1][3], k23);
      PK_LO(s23, qq[1][4], k45); PK_HI(s23, qq[1][5], k45);
      PK_LO(s23, qq[1][6], k67); PK_HI(s23, qq[1][7], k67);
      const float e0 = __expf(s01[0]), e1 = __expf(s01[1]);
      const float e2 = __expf(s23[0]), e3 = __expf(s23[1]);
      lsum[0] += e0; lsum[1] += e1; lsum[2] += e2; lsum[3] += e3;
      *(float4*)&pst[ni*68 + (rq<<2)] = make_float4(e0, e1, e2, e3);
    }
    __syncthreads();
    // PV: half h handles 32 ni; thread (mg, cq): 8m x 4c tile.
    // 3 b128 reads per ni per thread (32 FMA) — 96 wave-instrs/chunk.
    #pragma unroll 4
    for (int i = 0; i < 32; ++i) {
      const int ni = (h << 5) + i;
      const f32x4v pa = *(const f32x4v*)&pst[ni*68 + (mg<<3)];
      const f32x4v pb = *(const f32x4v*)&pst[ni*68 + (mg<<3) + 4];
      const f32x4v va = *(const f32x4v*)&vst[ni*68 + (cq<<2)];
      const f32x2 p01 = __builtin_shufflevector(pa, pa, 0, 1);
      const f32x2 p23 = __builtin_shufflevector(pa, pa, 2, 3);
      const f32x2 p45 = __builtin_shufflevector(pb, pb, 0, 1);
      const f32x2 p67 = __builtin_shufflevector(pb, pb, 2, 3);
      const f32x2 v01 = __builtin_shufflevector(va, va, 0, 1);
      const f32x2 v23 = __builtin_shufflevector(va, va, 2, 3);
      PK_LO(A2[0][0], p01, v01); PK_LO(A2[0][1], p23, v01);
      PK_LO(A2[0][2], p45, v01); PK_LO(A2[0][3], p67, v01);
      PK_HI(A2[1][0], p01, v01); PK_HI(A2[1][1], p23, v01);
      PK_HI(A2[1][2], p45, v01); PK_HI(A2[1][3], p67, v01);
      PK_LO(A2[2][0], p01, v23); PK_LO(A2[2][1], p23, v23);
      PK_LO(A2[2][2], p45, v23); PK_LO(A2[2][3], p67, v23);
      PK_HI(A2[3][0], p01, v23); PK_HI(A2[3][1], p23, v23);
      PK_HI(A2[3][2], p45, v23); PK_HI(A2[3][3], p67, v23);
    }
  }
  // ---- single-round merge: wave2->pst, wave3->vst; waves 0/1 accumulate ----
  __syncthreads();               // all PV reads of vst/pst done
  if (h == 1) {
    float* buf = (wv == 2) ? pst : vst;     // wave2 pairs wave0, wave3 pairs wave1
    #pragma unroll
    for (int c = 0; c < 4; ++c) {
      f32x4v lo = __builtin_shufflevector(A2[c][0], A2[c][1], 0,1,2,3);
      f32x4v hi = __builtin_shufflevector(A2[c][2], A2[c][3], 0,1,2,3);
      *(f32x4v*)&buf[li*34 + (c<<3)]     = lo;
      *(f32x4v*)&buf[li*34 + (c<<3) + 4] = hi;
    }
  }
  __syncthreads();
  if (h == 0) {
    const float* buf = (wv == 0) ? pst : vst;
    #pragma unroll
    for (int c = 0; c < 4; ++c) {
      f32x4v lo = *(const f32x4v*)&buf[li*34 + (c<<3)];
      f32x4v hi = *(const f32x4v*)&buf[li*34 + (c<<3) + 4];
      A2[c][0][0] += lo[0]; A2[c][0][1] += lo[1];
      A2[c][1][0] += lo[2]; A2[c][1][1] += lo[3];
      A2[c][2][0] += hi[0]; A2[c][2][1] += hi[1];
      A2[c][3][0] += hi[2]; A2[c][3][1] += hi[3];
    }
  }
  __syncthreads();               // merge reads done before pst reused for lsum
  // lsum partials into pst scratch (r13 mapping) -> lp
  *(float4*)&pst[sg*68 + (rq<<2)] = make_float4(lsum[0], lsum[1], lsum[2], lsum[3]);
  __syncthreads();
  if (t < 64) {
    float l = 0.f;
    #pragma unroll
    for (int s = 0; s < 16; ++s) l += pst[s*68 + t];
    __hip_atomic_store(&lp[(((((g<<2)|b)<<6) | mt)<<6) | t], l,
                       __ATOMIC_RELAXED, __HIP_MEMORY_SCOPE_AGENT);
  }
  // waves 0/1: op partial stores from registers, r13-identical layout
  if (h == 0) {
    float* ob = op + ((size_t)((((g<<2)|b)<<6) | mt) << 12);
    #pragma unroll
    for (int mp = 0; mp < 4; ++mp)
      #pragma unroll
      for (int e = 0; e < 2; ++e) {
        const int row = (mg<<3) + (mp<<1) + e;
        const int base = (row<<6) | (cq<<2);
        f2u lo, hi;
        lo.f[0] = A2[0][mp][e]; lo.f[1] = A2[1][mp][e];
        hi.f[0] = A2[2][mp][e]; hi.f[1] = A2[3][mp][e];
        __hip_atomic_store((u64*)&ob[base],     lo.u, __ATOMIC_RELAXED, __HIP_MEMORY_SCOPE_AGENT);
        __hip_atomic_store((u64*)&ob[base + 2], hi.u, __ATOMIC_RELAXED, __HIP_MEMORY_SCOPE_AGENT);
      }
  }

  // ---- arrival protocol (r10-proven) ----
  __syncthreads();
  if (t == 0)
    who = __hip_atomic_fetch_add(&cnt[(b<<6) | mt], 1,
                                 __ATOMIC_RELEASE, __HIP_MEMORY_SCOPE_AGENT);
  __syncthreads();
  if (who != 3) return;
  if (t == 0)
    __builtin_amdgcn_fence(__ATOMIC_ACQUIRE, "agent");  // buffer_inv: drop stale L2
  __syncthreads();

  // ---- inline G-merge (r10-proven; plain loads post-invalidate) ----
  float* sm = vst;
  float* linv = kst;
  if (t < 64) {
    float l = 0.f;
    #pragma unroll
    for (int g2 = 0; g2 < 4; ++g2)
      l += lp[(((((g2<<2)|b)<<6) | mt)<<6) | t];
    linv[t] = 1.f / l;
  }
  __syncthreads();
  for (int i = 0; i < 16; ++i) {
    int idx = (i<<8) + t;
    float s = 0.f;
    #pragma unroll
    for (int g2 = 0; g2 < 4; ++g2)
      s += op[((size_t)((((g2<<2)|b)<<6) | mt) << 12) + idx];
    int m = idx >> 6, c = idx & 63;
    sm[c*65 + m] = s * linv[m];
  }
  __syncthreads();
  for (int i = 0; i < 16; ++i) {
    int idx = (i<<8) + t;
    int m = idx & 63, c = idx >> 6;
    float ov = sm[c*65 + m];
    o[(((b<<6)|c)<<12) | (mt<<6) | m] = ov;
    float s1 = ov, s2 = ov*ov;
    #pragma unroll
    for (int off2 = 32; off2; off2 >>= 1) {
      s1 += __shfl_xor(s1, off2, 64);
      s2 += __shfl_xor(s2, off2, 64);
    }
    if ((t & 63) == 0) { atomicAdd(&psums[c], s1); atomicAdd(&psums[64+c], s2); }
  }
}

// ---------------- yg: BN1 coefs + y = o*A1+B1+x + gram partials ----------------
// (verbatim round 12/13 — passed)
__global__ __launch_bounds__(256) void yg_kernel(
    const float* __restrict__ o, const float* __restrict__ x,
    const float* __restrict__ psums,
    const float* __restrict__ gp, const float* __restrict__ w1, const float* __restrict__ bb1,
    float* __restrict__ y, float* __restrict__ gpart) {
  __shared__ float yt[64*36];    // [c][m32], stride 36
  __shared__ float cf[128];
  const int bi = blockIdx.x;
  const int b = bi >> 7, sp = bi & 127;
  const int t = threadIdx.x;
  const int n0 = sp << 5;
  if (t < 64) {
    float m1 = psums[t] * (1.f/16384.f), m2 = psums[64+t] * (1.f/16384.f);
    float var = m2 - m1*m1;
    float gg = *gp;
    float r = rsqrtf(gg*gg*var + EPS);
    float a = gg * r * w1[t];
    cf[t] = a; cf[64+t] = bb1[t] - m1*a;
  }
  __syncthreads();
  #pragma unroll
  for (int i = 0; i < 8; ++i) {
    int idx = (i<<8) + t;
    int c = idx >> 5, m = idx & 31;
    size_t gi = ((size_t)(((b<<6)|c)<<12)) + n0 + m;
    float yv = o[gi]*cf[c] + cf[64+c] + x[gi];
    yt[c*36 + m] = yv;
    y[gi] = yv;
  }
  __syncthreads();
  {
    int tc = t >> 4, td = t & 15;
    float acc[4][4] = {{0.f}};
    #pragma unroll
    for (int mj = 0; mj < 8; ++mj) {
      float4 ya[4], yb[4];
      #pragma unroll
      for (int r = 0; r < 4; ++r)  ya[r] = *(const float4*)&yt[((tc<<2)+r)*36 + (mj<<2)];
      #pragma unroll
      for (int ss = 0; ss < 4; ++ss) yb[ss] = *(const float4*)&yt[((td<<2)+ss)*36 + (mj<<2)];
      #pragma unroll
      for (int r = 0; r < 4; ++r)
        #pragma unroll
        for (int ss = 0; ss < 4; ++ss)
          acc[r][ss] += ya[r].x*yb[ss].x + ya[r].y*yb[ss].y + ya[r].z*yb[ss].z + ya[r].w*yb[ss].w;
    }
    float* gb = gpart + ((size_t)bi << 12);
    #pragma unroll
    for (int r = 0; r < 4; ++r)
      *(float4*)&gb[(((tc<<2)+r)<<6) | (td<<2)] =
          make_float4(acc[r][0], acc[r][1], acc[r][2], acc[r][3]);
  }
}

// ---------------- csm: reduce 128 gram partials + row softmax -> attnc ----------------
// (verbatim round 12/13 — passed)
__global__ __launch_bounds__(256) void csm_kernel(
    const float* __restrict__ gpart, float* __restrict__ attnc) {
  __shared__ float red[256];
  const int bi = blockIdx.x;
  const int b = bi >> 6, row = bi & 63;
  const int t = threadIdx.x;
  const int d = t & 63, spg = t >> 6;
  float e = 0.f;
  #pragma unroll
  for (int jj = 0; jj < 32; ++jj) {
    int ch = (spg<<5) + jj;
    e += gpart[((size_t)((b<<7)|ch) << 12) + (row<<6) + d];
  }
  red[t] = e;
  __syncthreads();
  if (t < 64) {
    float ee = red[t]+red[64+t]+red[128+t]+red[192+t];
    float mn = ee;
    #pragma unroll
    for (int off = 32; off; off >>= 1) mn = fminf(mn, __shfl_xor(mn, off, 64));
    float p = __expf(mn - ee);           // softmax(max-e) == exp(min-e)/sum
    float s = p;
    #pragma unroll
    for (int off = 32; off; off >>= 1) s += __shfl_xor(s, off, 64);
    attnc[(((b<<6)|row)<<6) | t] = p / s;
  }
}

// ---------------- out_c = attn_c @ y  (+ fused BN2 stats) ----------------
// (verbatim round 12/13 — passed)
__global__ __launch_bounds__(256) void cam_apply_kernel(
    const float* __restrict__ attn, const float* __restrict__ y,
    float* __restrict__ oc, float* __restrict__ sums) {
  __shared__ float satt[64*68];
  const int bi = blockIdx.x;
  const int b = bi >> 7, sp = bi & 127;
  const int n0 = sp << 5;
  const int t = threadIdx.x;
  const int nl = t & 31, cg_ = t >> 5;
  for (int i = t; i < 4096; i += 256)
    satt[(i>>6)*68 + (i&63)] = attn[(b<<12) | i];
  __syncthreads();
  float yv[64];
  #pragma unroll
  for (int d = 0; d < 64; ++d)
    yv[d] = y[((size_t)(((b<<6)|d)<<12)) + n0 + nl];
  #pragma unroll
  for (int j = 0; j < 8; ++j) {
    int c = (cg_<<3) + j;
    float acc = 0.f;
    #pragma unroll
    for (int d4 = 0; d4 < 16; ++d4) {
      float4 avv = *(const float4*)&satt[c*68 + (d4<<2)];
      acc += avv.x*yv[d4*4] + avv.y*yv[d4*4+1] + avv.z*yv[d4*4+2] + avv.w*yv[d4*4+3];
    }
    oc[((size_t)(((b<<6)|c)<<12)) + n0 + nl] = acc;
    float s1 = acc, s2 = acc*acc;
    #pragma unroll
    for (int off = 16; off; off >>= 1) {
      s1 += __shfl_xor(s1, off, 64);
      s2 += __shfl_xor(s2, off, 64);
    }
    if ((t & 31) == 0) { atomicAdd(&sums[c], s1); atomicAdd(&sums[64+c], s2); }
  }
}

// ---------------- fin: BN2 coefs + out = oc*A2 + B2 + y (elementwise) ----------------
// (verbatim round 12/13 — passed)
__global__ __launch_bounds__(256) void fin_kernel(
    const float* __restrict__ oc, const float* __restrict__ y,
    const float* __restrict__ s2b,
    const float* __restrict__ gc, const float* __restrict__ w2, const float* __restrict__ bb2,
    float* __restrict__ out) {
  __shared__ float cf[128];
  const int t = threadIdx.x;
  if (t < 64) {
    float m1 = s2b[t] * (1.f/16384.f), m2 = s2b[64+t] * (1.f/16384.f);
    float var = m2 - m1*m1;
    float gg = *gc;
    float r = rsqrtf(gg*gg*var + EPS);
    float a = gg * r * w2[t];
    cf[t] = a; cf[64+t] = bb2[t] - m1*a;
  }
  __syncthreads();
  const int off = (blockIdx.x*256 + t) << 2;
  const int c = (off >> 12) & 63;
  const float a = cf[c], bb = cf[64+c];
  const float4 o4 = *(const float4*)&oc[off];
  const float4 y4 = *(const float4*)&y[off];
  float4 r4;
  r4.x = o4.x*a + bb + y4.x;
  r4.y = o4.y*a + bb + y4.y;
  r4.z = o4.z*a + bb + y4.z;
  r4.w = o4.w*a + bb + y4.w;
  *(float4*)&out[off] = r4;
}

extern "C" void kernel_launch(void* const* d_in, const int* in_sizes, int n_in,
                              void* d_out, int out_size, void* d_ws, size_t ws_size,
                              hipStream_t stream) {
  (void)in_sizes; (void)n_in; (void)out_size; (void)ws_size;
  const float* x      = (const float*)d_in[0];
  const float* Wq     = (const float*)d_in[1];
  const float* bq     = (const float*)d_in[2];
  const float* Wk     = (const float*)d_in[3];
  const float* bk     = (const float*)d_in[4];
  const float* Wv     = (const float*)d_in[5];
  const float* bv     = (const float*)d_in[6];
  const float* gp     = (const float*)d_in[7];
  const float* bnp_w  = (const float*)d_in[8];
  const float* bnp_b  = (const float*)d_in[9];
  const float* gc     = (const float*)d_in[10];
  const float* bnc_w  = (const float*)d_in[11];
  const float* bnc_b  = (const float*)d_in[12];

  float* ws = (float*)d_ws;
  float* q     = ws + Q_OFF;
  float* k     = ws + K_OFF;
  float* v     = ws + V_OFF;
  float* o     = ws + O_OFF;
  float* y     = ws + Y_OFF;
  float* oc    = ws + OC_OFF;
  float* atc   = ws + AT_OFF;
  float* s2b   = ws + S2_OFF;
  float* ps    = ws + PS_OFF;
  int*   cnt   = (int*)(ws + CNT_OFF);
  float* op    = ws + OP_OFF;
  float* lpart = ws + LP_OFF;
  float* gpart = op;             // aliases op region (dead after attn)

  // zero s2b(128) + ps(128) + cnt(256) — contiguous 512 words
  hipMemsetAsync(s2b, 0, 512u * sizeof(float), stream);

  proj_kernel<<<256, 256, 0, stream>>>(x, Wq, bq, Wk, bk, Wv, bv, q, k, v);
  attn_kernel<<<1024, 256, 0, stream>>>(q, k, v, op, lpart, o, ps, cnt);
  yg_kernel<<<512, 256, 0, stream>>>(o, x, ps, gp, bnp_w, bnp_b, y, gpart);
  csm_kernel<<<256, 256, 0, stream>>>(gpart, atc);
  cam_apply_kernel<<<512, 256, 0, stream>>>(atc, y, oc, s2b);
  fin_kernel<<<1024, 256, 0, stream>>>(oc, y, s2b, gc, bnc_w, bnc_b, (float*)d_out);
}

// Round 16
// 424.866 us; speedup vs baseline: 1.5516x; 1.1042x over previous
//
#include <hip/hip_runtime.h>

#define NN 4096
#define EPS 1e-5f

typedef unsigned long long u64;
union f2u { float f[2]; u64 u; };
typedef float f32x2 __attribute__((ext_vector_type(2)));
typedef float f32x4v __attribute__((ext_vector_type(4)));

// packed fp32 FMA with op_sel broadcast of src1 (VOP3P, 2 FMA/instr):
//  PK_LO: acc.lo += a.lo*b.lo ; acc.hi += a.hi*b.lo   (b.lo broadcast)
//  PK_HI: acc.lo += a.lo*b.hi ; acc.hi += a.hi*b.hi   (b.hi broadcast)
#define PK_LO(acc, a, b) \
  asm("v_pk_fma_f32 %0, %1, %2, %0 op_sel:[0,0,0] op_sel_hi:[1,0,1]" \
      : "+v"(acc) : "v"(a), "v"(b))
#define PK_HI(acc, a, b) \
  asm("v_pk_fma_f32 %0, %1, %2, %0 op_sel:[0,1,0] op_sel_hi:[1,1,1]" \
      : "+v"(acc) : "v"(a), "v"(b))

// ---------------- workspace layout (float offsets) ----------------
#define Q_OFF   0u              // [B][N][8]      131072
#define K_OFF   131072u         // [B][8][N]      131072
#define V_OFF   262144u         // [B][64][N]    1048576
#define O_OFF   1310720u        // PAM out [B][64][N]
#define Y_OFF   2359296u        // y [B][64][N]
#define OC_OFF  3407872u        // CAM raw out
#define AT_OFF  4456448u        // attn_c [B][64][64] 16384
#define S2_OFF  4472832u        // CAM sums: sum[64], sumsq[64]
#define PS_OFF  4472960u        // PAM sums: sum[64], sumsq[64]
#define CNT_OFF 4473088u        // per-(b,mt) arrival counters [256] int32
#define OP_OFF  4473344u        // attn partials [G=4][B][64mt][64m][64c] (4*1048576)
#define LP_OFF  8667648u        // partial row sums [G=4][B][64mt][64m] (4*16384)
// gpart ALIASES op region (op/lp dead after attn kernel)

// ---------------- projections: q,k,v (x staged via LDS) ----------------
// (verbatim r6-r13 — passed)
__global__ __launch_bounds__(256) void proj_kernel(
    const float* __restrict__ x, const float* __restrict__ Wq, const float* __restrict__ bq,
    const float* __restrict__ Wk, const float* __restrict__ bk,
    const float* __restrict__ Wv, const float* __restrict__ bv,
    float* __restrict__ q, float* __restrict__ k, float* __restrict__ v) {
  __shared__ float sWq[8*64], sWk[8*64], sWv[64*64], sbq[8], sbk[8], sbv[64];
  __shared__ float xt[64*68];
  int t = threadIdx.x;
  int b = blockIdx.x >> 6;
  int sp = blockIdx.x & 63;
  int n0 = sp << 6;
  for (int i = t; i < 512; i += 256) { sWq[i] = Wq[i]; sWk[i] = Wk[i]; }
  for (int i = t; i < 4096; i += 256) sWv[i] = Wv[i];
  if (t < 64) sbv[t] = bv[t];
  if (t < 8) { sbq[t] = bq[t]; sbk[t] = bk[t]; }
  for (int i = t; i < 1024; i += 256) {
    int c = i >> 4, nf = (i & 15) << 2;
    *(float4*)&xt[c*68 + nf] =
        *(const float4*)&x[(size_t)(((b<<6)|c)<<12) + n0 + nf];
  }
  __syncthreads();
  int nl = t & 63;
  int n = n0 | nl;
  int cg_ = t >> 6;
  float xv[64];
  #pragma unroll
  for (int c = 0; c < 64; ++c) xv[c] = xt[c*68 + nl];
  for (int c = cg_*16; c < cg_*16+16; ++c) {
    float acc = sbv[c];
    #pragma unroll
    for (int c2 = 0; c2 < 64; ++c2) acc += sWv[c*64 + c2] * xv[c2];
    v[(((b<<6)|c)<<12) | n] = acc;
  }
  if (cg_ == 0) {
    #pragma unroll
    for (int d = 0; d < 8; ++d) {
      float acc = sbq[d];
      #pragma unroll
      for (int c = 0; c < 64; ++c) acc += sWq[d*64+c] * xv[c];
      q[(((b<<12)|n)<<3) | d] = acc;
    }
  } else if (cg_ == 1) {
    #pragma unroll
    for (int d = 0; d < 8; ++d) {
      float acc = sbk[d];
      #pragma unroll
      for (int c = 0; c < 64; ++c) acc += sWk[d*64+c] * xv[c];
      k[(((b<<3)|d)<<12) | n] = acc;
    }
  }
}

// ---------------- flash attention (PAM): r13 core + prefetch staging ----
// r13 verbatim (packed pk_fma scores/PV, 4x4 tile, in-kernel last-block
// merge) with ONE change: the next chunk's 18 global loads are issued at
// the top of the iteration into registers and committed to LDS only after
// the PV barrier — the vmcnt wait lands after ~4us of compute instead of
// immediately (r7's idea retried at 4 blocks/CU where r13's TLP regime
// holds).  Staged values and all downstream code byte-identical to r13.
__global__ __launch_bounds__(256, 4) void attn_kernel(
    const float* __restrict__ q, const float* __restrict__ k,
    const float* __restrict__ v, float* __restrict__ op,
    float* __restrict__ lp, float* __restrict__ o,
    float* __restrict__ psums, int* __restrict__ cnt) {
  __shared__ float kst[64*12];   // [ni][d], pad 12; merge: linv[64]
  __shared__ float vst[64*68];   // [ni][c], pad 68; merge: sm[c][m] pad 65
  __shared__ float pst[64*68];   // [ni][m], pad 68 (+ lsum scratch)
  __shared__ int who;

  const int bi   = blockIdx.x;
  const int g    = bi & 3;
  const int rest = bi >> 2;
  const int mt   = rest & 63;
  const int b    = rest >> 6;
  const int m0   = mt << 6;
  const int t    = threadIdx.x;

  const int rq = t & 15;        // score mapping: rows 4rq..4rq+3
  const int sg = t >> 4;        // score mapping: ni 4sg..4sg+3

  // staging helpers (fixed per thread; same elements as r13's loops)
  const int kn  = t & 63;
  const int kd0 = t >> 6, kd1 = kd0 + 4;
  const size_t kgb = (size_t)(b << 3) << 12;
  const size_t vgb = (size_t)(b << 6) << 12;

  // q rows interleaved as pairs (r13-proven)
  f32x2 qq[2][8];
  {
    f32x4v rowv[4][2];
    #pragma unroll
    for (int r = 0; r < 4; ++r) {
      const f32x4v* qp = (const f32x4v*)&q[(size_t)(((b<<12) | (m0 + (rq<<2) + r)) << 3)];
      rowv[r][0] = qp[0]; rowv[r][1] = qp[1];
    }
    #pragma unroll
    for (int p = 0; p < 2; ++p)
      #pragma unroll
      for (int j = 0; j < 8; ++j) {
        f32x2 w;
        w[0] = rowv[2*p][j>>2][j&3];
        w[1] = rowv[2*p+1][j>>2][j&3];
        qq[p][j] = w;
      }
  }

  float lsum[4] = {0.f, 0.f, 0.f, 0.f};
  f32x2 A2[4][2];                // [c][mpair]; av[m][c] = A2[c][m>>1][m&1]
  #pragma unroll
  for (int c = 0; c < 4; ++c) { A2[c][0] = (f32x2){0.f,0.f}; A2[c][1] = (f32x2){0.f,0.f}; }

  const int span = NN >> 2;
  const int nbeg = g * span;
  const int nend = nbeg + span;

  // prologue: stage chunk nbeg directly into LDS
  kst[kn*12 + kd0] = k[kgb + ((size_t)kd0<<12) + nbeg + kn];
  kst[kn*12 + kd1] = k[kgb + ((size_t)kd1<<12) + nbeg + kn];
  #pragma unroll
  for (int j = 0; j < 16; ++j) {
    const int c = kd0 + (j<<2);
    vst[kn*68 + c] = v[vgb + ((size_t)c<<12) + nbeg + kn];
  }

  for (int n0 = nbeg; n0 < nend; n0 += 64) {
    __syncthreads();             // staged LDS (prologue or reg-commit) visible
    const int n1 = n0 + 64;
    const bool more = n1 < nend;
    // issue next-chunk loads into registers (wait deferred to after PV)
    float kr0, kr1, vr[16];
    if (more) {
      kr0 = k[kgb + ((size_t)kd0<<12) + n1 + kn];
      kr1 = k[kgb + ((size_t)kd1<<12) + n1 + kn];
      #pragma unroll
      for (int j = 0; j < 16; ++j) {
        const int c = kd0 + (j<<2);
        vr[j] = v[vgb + ((size_t)c<<12) + n1 + kn];
      }
    }
    // scores (r13 packed): thread (rq, sg) -> rows 4rq.., ni 4sg..+3
    #pragma unroll
    for (int j4 = 0; j4 < 4; ++j4) {
      const int ni = (sg << 2) | j4;
      const f32x4v ka = *(const f32x4v*)&kst[ni*12];
      const f32x4v kb = *(const f32x4v*)&kst[ni*12 + 4];
      const f32x2 k01 = __builtin_shufflevector(ka, ka, 0, 1);
      const f32x2 k23 = __builtin_shufflevector(ka, ka, 2, 3);
      const f32x2 k45 = __builtin_shufflevector(kb, kb, 0, 1);
      const f32x2 k67 = __builtin_shufflevector(kb, kb, 2, 3);
      f32x2 s01 = (f32x2){0.f,0.f}, s23 = (f32x2){0.f,0.f};
      PK_LO(s01, qq[0][0], k01); PK_HI(s01, qq[0][1], k01);
      PK_LO(s01, qq[0][2], k23); PK_HI(s01, qq[0][3], k23);
      PK_LO(s01, qq[0][4], k45); PK_HI(s01, qq[0][5], k45);
      PK_LO(s01, qq[0][6], k67); PK_HI(s01, qq[0][7], k67);
      PK_LO(s23, qq[1][0], k01); PK_HI(s23, qq[1][1], k01);
      PK_LO(s23, qq[1][2], k23); PK_HI(s23, qq[1][3], k23);
      PK_LO(s23, qq[1][4], k45); PK_HI(s23, qq[1][5], k45);
      PK_LO(s23, qq[1][6], k67); PK_HI(s23, qq[1][7], k67);
      const float e0 = __expf(s01[0]), e1 = __expf(s01[1]);
      const float e2 = __expf(s23[0]), e3 = __expf(s23[1]);
      lsum[0] += e0; lsum[1] += e1; lsum[2] += e2; lsum[3] += e3;
      *(float4*)&pst[ni*68 + (rq<<2)] = make_float4(e0, e1, e2, e3);
    }
    __syncthreads();             // pst ready (kst reads done)
    // PV (r13 packed): 8 pk_fma / ni, v components broadcast via op_sel
    #pragma unroll 4
    for (int ni = 0; ni < 64; ++ni) {
      const f32x4v p4 = *(const f32x4v*)&pst[ni*68 + (sg<<2)];
      const f32x4v v4 = *(const f32x4v*)&vst[ni*68 + (rq<<2)];
      const f32x2 pa = __builtin_shufflevector(p4, p4, 0, 1);
      const f32x2 pb = __builtin_shufflevector(p4, p4, 2, 3);
      const f32x2 va = __builtin_shufflevector(v4, v4, 0, 1);
      const f32x2 vb = __builtin_shufflevector(v4, v4, 2, 3);
      PK_LO(A2[0][0], pa, va); PK_LO(A2[0][1], pb, va);
      PK_HI(A2[1][0], pa, va); PK_HI(A2[1][1], pb, va);
      PK_LO(A2[2][0], pa, vb); PK_LO(A2[2][1], pb, vb);
      PK_HI(A2[3][0], pa, vb); PK_HI(A2[3][1], pb, vb);
    }
    __syncthreads();             // PV reads of vst/pst done
    // commit prefetched regs to LDS (vmcnt wait lands HERE, after compute)
    if (more) {
      kst[kn*12 + kd0] = kr0;
      kst[kn*12 + kd1] = kr1;
      #pragma unroll
      for (int j = 0; j < 16; ++j) {
        const int c = kd0 + (j<<2);
        vst[kn*68 + c] = vr[j];
      }
    }
  }
  // reduce lsum across the 16 sg groups via pst scratch, write lp partial
  // (all waves passed the final in-loop barrier; pst readers done)
  *(float4*)&pst[sg*68 + (rq<<2)] = make_float4(lsum[0], lsum[1], lsum[2], lsum[3]);
  __syncthreads();
  if (t < 64) {
    float l = 0.f;
    #pragma unroll
    for (int s = 0; s < 16; ++s) l += pst[s*68 + t];
    __hip_atomic_store(&lp[(((((g<<2)|b)<<6) | mt)<<6) | t], l,
                       __ATOMIC_RELAXED, __HIP_MEMORY_SCOPE_AGENT);
  }
  // write unnormalized partial av (device-scope relaxed, 8B granules, L2-clean)
  float* ob = op + ((size_t)((((g<<2)|b)<<6) | mt) << 12);
  #pragma unroll
  for (int r = 0; r < 4; ++r) {
    const int base = (((sg<<2)|r)<<6) | (rq<<2);
    const int h = r >> 1, e = r & 1;
    f2u lo, hi;
    lo.f[0] = A2[0][h][e]; lo.f[1] = A2[1][h][e];
    hi.f[0] = A2[2][h][e]; hi.f[1] = A2[3][h][e];
    __hip_atomic_store((u64*)&ob[base],     lo.u, __ATOMIC_RELAXED, __HIP_MEMORY_SCOPE_AGENT);
    __hip_atomic_store((u64*)&ob[base + 2], hi.u, __ATOMIC_RELAXED, __HIP_MEMORY_SCOPE_AGENT);
  }

  // ---- arrival protocol (r10-proven) ----
  __syncthreads();
  if (t == 0)
    who = __hip_atomic_fetch_add(&cnt[(b<<6) | mt], 1,
                                 __ATOMIC_RELEASE, __HIP_MEMORY_SCOPE_AGENT);
  __syncthreads();
  if (who != 3) return;
  if (t == 0)
    __builtin_amdgcn_fence(__ATOMIC_ACQUIRE, "agent");  // buffer_inv: drop stale L2
  __syncthreads();

  // ---- inline G-merge (r10-proven; plain loads post-invalidate) ----
  float* sm = vst;
  float* linv = kst;
  if (t < 64) {
    float l = 0.f;
    #pragma unroll
    for (int g2 = 0; g2 < 4; ++g2)
      l += lp[(((((g2<<2)|b)<<6) | mt)<<6) | t];
    linv[t] = 1.f / l;
  }
  __syncthreads();
  for (int i = 0; i < 16; ++i) {
    int idx = (i<<8) + t;
    float s = 0.f;
    #pragma unroll
    for (int g2 = 0; g2 < 4; ++g2)
      s += op[((size_t)((((g2<<2)|b)<<6) | mt) << 12) + idx];
    int m = idx >> 6, c = idx & 63;
    sm[c*65 + m] = s * linv[m];
  }
  __syncthreads();
  for (int i = 0; i < 16; ++i) {
    int idx = (i<<8) + t;
    int m = idx & 63, c = idx >> 6;
    float ov = sm[c*65 + m];
    o[(((b<<6)|c)<<12) | (mt<<6) | m] = ov;
    float s1 = ov, s2 = ov*ov;
    #pragma unroll
    for (int off2 = 32; off2; off2 >>= 1) {
      s1 += __shfl_xor(s1, off2, 64);
      s2 += __shfl_xor(s2, off2, 64);
    }
    if ((t & 63) == 0) { atomicAdd(&psums[c], s1); atomicAdd(&psums[64+c], s2); }
  }
}

// ---------------- yg: BN1 coefs + y = o*A1+B1+x + gram partials ----------------
// (verbatim round 12/13 — passed)
__global__ __launch_bounds__(256) void yg_kernel(
    const float* __restrict__ o, const float* __restrict__ x,
    const float* __restrict__ psums,
    const float* __restrict__ gp, const float* __restrict__ w1, const float* __restrict__ bb1,
    float* __restrict__ y, float* __restrict__ gpart) {
  __shared__ float yt[64*36];    // [c][m32], stride 36
  __shared__ float cf[128];
  const int bi = blockIdx.x;
  const int b = bi >> 7, sp = bi & 127;
  const int t = threadIdx.x;
  const int n0 = sp << 5;
  if (t < 64) {
    float m1 = psums[t] * (1.f/16384.f), m2 = psums[64+t] * (1.f/16384.f);
    float var = m2 - m1*m1;
    float gg = *gp;
    float r = rsqrtf(gg*gg*var + EPS);
    float a = gg * r * w1[t];
    cf[t] = a; cf[64+t] = bb1[t] - m1*a;
  }
  __syncthreads();
  #pragma unroll
  for (int i = 0; i < 8; ++i) {
    int idx = (i<<8) + t;
    int c = idx >> 5, m = idx & 31;
    size_t gi = ((size_t)(((b<<6)|c)<<12)) + n0 + m;
    float yv = o[gi]*cf[c] + cf[64+c] + x[gi];
    yt[c*36 + m] = yv;
    y[gi] = yv;
  }
  __syncthreads();
  {
    int tc = t >> 4, td = t & 15;
    float acc[4][4] = {{0.f}};
    #pragma unroll
    for (int mj = 0; mj < 8; ++mj) {
      float4 ya[4], yb[4];
      #pragma unroll
      for (int r = 0; r < 4; ++r)  ya[r] = *(const float4*)&yt[((tc<<2)+r)*36 + (mj<<2)];
      #pragma unroll
      for (int ss = 0; ss < 4; ++ss) yb[ss] = *(const float4*)&yt[((td<<2)+ss)*36 + (mj<<2)];
      #pragma unroll
      for (int r = 0; r < 4; ++r)
        #pragma unroll
        for (int ss = 0; ss < 4; ++ss)
          acc[r][ss] += ya[r].x*yb[ss].x + ya[r].y*yb[ss].y + ya[r].z*yb[ss].z + ya[r].w*yb[ss].w;
    }
    float* gb = gpart + ((size_t)bi << 12);
    #pragma unroll
    for (int r = 0; r < 4; ++r)
      *(float4*)&gb[(((tc<<2)+r)<<6) | (td<<2)] =
          make_float4(acc[r][0], acc[r][1], acc[r][2], acc[r][3]);
  }
}

// ---------------- csm: reduce 128 gram partials + row softmax -> attnc ----------------
// (verbatim round 12/13 — passed)
__global__ __launch_bounds__(256) void csm_kernel(
    const float* __restrict__ gpart, float* __restrict__ attnc) {
  __shared__ float red[256];
  const int bi = blockIdx.x;
  const int b = bi >> 6, row = bi & 63;
  const int t = threadIdx.x;
  const int d = t & 63, spg = t >> 6;
  float e = 0.f;
  #pragma unroll
  for (int jj = 0; jj < 32; ++jj) {
    int ch = (spg<<5) + jj;
    e += gpart[((size_t)((b<<7)|ch) << 12) + (row<<6) + d];
  }
  red[t] = e;
  __syncthreads();
  if (t < 64) {
    float ee = red[t]+red[64+t]+red[128+t]+red[192+t];
    float mn = ee;
    #pragma unroll
    for (int off = 32; off; off >>= 1) mn = fminf(mn, __shfl_xor(mn, off, 64));
    float p = __expf(mn - ee);           // softmax(max-e) == exp(min-e)/sum
    float s = p;
    #pragma unroll
    for (int off = 32; off; off >>= 1) s += __shfl_xor(s, off, 64);
    attnc[(((b<<6)|row)<<6) | t] = p / s;
  }
}

// ---------------- out_c = attn_c @ y  (+ fused BN2 stats) ----------------
// (verbatim round 12/13 — passed)
__global__ __launch_bounds__(256) void cam_apply_kernel(
    const float* __restrict__ attn, const float* __restrict__ y,
    float* __restrict__ oc, float* __restrict__ sums) {
  __shared__ float satt[64*68];
  const int bi = blockIdx.x;
  const int b = bi >> 7, sp = bi & 127;
  const int n0 = sp << 5;
  const int t = threadIdx.x;
  const int nl = t & 31, cg_ = t >> 5;
  for (int i = t; i < 4096; i += 256)
    satt[(i>>6)*68 + (i&63)] = attn[(b<<12) | i];
  __syncthreads();
  float yv[64];
  #pragma unroll
  for (int d = 0; d < 64; ++d)
    yv[d] = y[((size_t)(((b<<6)|d)<<12)) + n0 + nl];
  #pragma unroll
  for (int j = 0; j < 8; ++j) {
    int c = (cg_<<3) + j;
    float acc = 0.f;
    #pragma unroll
    for (int d4 = 0; d4 < 16; ++d4) {
      float4 avv = *(const float4*)&satt[c*68 + (d4<<2)];
      acc += avv.x*yv[d4*4] + avv.y*yv[d4*4+1] + avv.z*yv[d4*4+2] + avv.w*yv[d4*4+3];
    }
    oc[((size_t)(((b<<6)|c)<<12)) + n0 + nl] = acc;
    float s1 = acc, s2 = acc*acc;
    #pragma unroll
    for (int off = 16; off; off >>= 1) {
      s1 += __shfl_xor(s1, off, 64);
      s2 += __shfl_xor(s2, off, 64);
    }
    if ((t & 31) == 0) { atomicAdd(&sums[c], s1); atomicAdd(&sums[64+c], s2); }
  }
}

// ---------------- fin: BN2 coefs + out = oc*A2 + B2 + y (elementwise) ----------------
// (verbatim round 12/13 — passed)
__global__ __launch_bounds__(256) void fin_kernel(
    const float* __restrict__ oc, const float* __restrict__ y,
    const float* __restrict__ s2b,
    const float* __restrict__ gc, const float* __restrict__ w2, const float* __restrict__ bb2,
    float* __restrict__ out) {
  __shared__ float cf[128];
  const int t = threadIdx.x;
  if (t < 64) {
    float m1 = s2b[t] * (1.f/16384.f), m2 = s2b[64+t] * (1.f/16384.f);
    float var = m2 - m1*m1;
    float gg = *gc;
    float r = rsqrtf(gg*gg*var + EPS);
    float a = gg * r * w2[t];
    cf[t] = a; cf[64+t] = bb2[t] - m1*a;
  }
  __syncthreads();
  const int off = (blockIdx.x*256 + t) << 2;
  const int c = (off >> 12) & 63;
  const float a = cf[c], bb = cf[64+c];
  const float4 o4 = *(const float4*)&oc[off];
  const float4 y4 = *(const float4*)&y[off];
  float4 r4;
  r4.x = o4.x*a + bb + y4.x;
  r4.y = o4.y*a + bb + y4.y;
  r4.z = o4.z*a + bb + y4.z;
  r4.w = o4.w*a + bb + y4.w;
  *(float4*)&out[off] = r4;
}

extern "C" void kernel_launch(void* const* d_in, const int* in_sizes, int n_in,
                              void* d_out, int out_size, void* d_ws, size_t ws_size,
                              hipStream_t stream) {
  (void)in_sizes; (void)n_in; (void)out_size; (void)ws_size;
  const float* x      = (const float*)d_in[0];
  const float* Wq     = (const float*)d_in[1];
  const float* bq     = (const float*)d_in[2];
  const float* Wk     = (const float*)d_in[3];
  const float* bk     = (const float*)d_in[4];
  const float* Wv     = (const float*)d_in[5];
  const float* bv     = (const float*)d_in[6];
  const float* gp     = (const float*)d_in[7];
  const float* bnp_w  = (const float*)d_in[8];
  const float* bnp_b  = (const float*)d_in[9];
  const float* gc     = (const float*)d_in[10];
  const float* bnc_w  = (const float*)d_in[11];
  const float* bnc_b  = (const float*)d_in[12];

  float* ws = (float*)d_ws;
  float* q     = ws + Q_OFF;
  float* k     = ws + K_OFF;
  float* v     = ws + V_OFF;
  float* o     = ws + O_OFF;
  float* y     = ws + Y_OFF;
  float* oc    = ws + OC_OFF;
  float* atc   = ws + AT_OFF;
  float* s2b   = ws + S2_OFF;
  float* ps    = ws + PS_OFF;
  int*   cnt   = (int*)(ws + CNT_OFF);
  float* op    = ws + OP_OFF;
  float* lpart = ws + LP_OFF;
  float* gpart = op;             // aliases op region (dead after attn)

  // zero s2b(128) + ps(128) + cnt(256) — contiguous 512 words
  hipMemsetAsync(s2b, 0, 512u * sizeof(float), stream);

  proj_kernel<<<256, 256, 0, stream>>>(x, Wq, bq, Wk, bk, Wv, bv, q, k, v);
  attn_kernel<<<1024, 256, 0, stream>>>(q, k, v, op, lpart, o, ps, cnt);
  yg_kernel<<<512, 256, 0, stream>>>(o, x, ps, gp, bnp_w, bnp_b, y, gpart);
  csm_kernel<<<256, 256, 0, stream>>>(gpart, atc);
  cam_apply_kernel<<<512, 256, 0, stream>>>(atc, y, oc, s2b);
  fin_kernel<<<1024, 256, 0, stream>>>(oc, y, s2b, gc, bnc_w, bnc_b, (float*)d_out);
}